// Round 1
// baseline (459.289 us; speedup 1.0000x reference)
//
#include <hip/hip_runtime.h>
#include <hip/hip_bf16.h>

#define B_   4
#define DENC 512
#define T_   200
#define DDEC 640
#define U_   100
#define H_   640
#define V_   1025
#define VPAD 1152   // 9 * 128

typedef float f32x4 __attribute__((ext_vector_type(4)));
typedef __bf16 bf16x8 __attribute__((ext_vector_type(8)));

// ---------------- K1: enc_proj[b,t,h] = sum_d enc[b,d,t] * W_enc[d,h] + b_enc[h]
__global__ __launch_bounds__(256) void enc_proj_kernel(
    const float* __restrict__ enc, const float* __restrict__ W,
    const float* __restrict__ bias, float* __restrict__ out)
{
    int hc = blockIdx.x, tt = blockIdx.y, b = blockIdx.z;
    int t0 = tt * 16, h0 = hc * 128;
    __shared__ float S[DENC][16];
    int tid = threadIdx.x;
    bool full = (t0 + 16 <= T_);
    for (int s = tid; s < DENC * 4; s += 256) {
        int d = s >> 2, j4 = (s & 3) * 4;
        const float* src = enc + ((size_t)b * DENC + d) * T_ + t0 + j4;
        if (full) {
            float4 v = *(const float4*)src;
            S[d][j4+0] = v.x; S[d][j4+1] = v.y; S[d][j4+2] = v.z; S[d][j4+3] = v.w;
        } else {
            #pragma unroll
            for (int c = 0; c < 4; ++c) {
                int t = t0 + j4 + c;
                S[d][j4+c] = (t < T_) ? src[c] : 0.f;
            }
        }
    }
    __syncthreads();
    int h = h0 + (tid & 127);
    int tg = tid >> 7;
    float acc[8] = {0.f,0.f,0.f,0.f,0.f,0.f,0.f,0.f};
    for (int d = 0; d < DENC; ++d) {
        float w = W[(size_t)d * H_ + h];
        const float* e = &S[d][tg * 8];
        #pragma unroll
        for (int i = 0; i < 8; ++i) acc[i] += w * e[i];
    }
    float bb = bias[h];
    #pragma unroll
    for (int i = 0; i < 8; ++i) {
        int t = t0 + tg * 8 + i;
        if (t < T_) out[((size_t)b * T_ + t) * H_ + h] = acc[i] + bb;
    }
}

// ---------------- K2: dec_proj[b,u,h] = sum_d dec[b,d,u] * W_pred[d,h] + b_pred[h]
__global__ __launch_bounds__(256) void dec_proj_kernel(
    const float* __restrict__ dec, const float* __restrict__ W,
    const float* __restrict__ bias, float* __restrict__ out)
{
    int hc = blockIdx.x, ut = blockIdx.y, b = blockIdx.z;
    int u0 = ut * 16, h0 = hc * 128;
    __shared__ float S[DDEC][16];
    int tid = threadIdx.x;
    bool full = (u0 + 16 <= U_);
    for (int s = tid; s < DDEC * 4; s += 256) {
        int d = s >> 2, j4 = (s & 3) * 4;
        const float* src = dec + ((size_t)b * DDEC + d) * U_ + u0 + j4;
        if (full) {
            float4 v = *(const float4*)src;
            S[d][j4+0] = v.x; S[d][j4+1] = v.y; S[d][j4+2] = v.z; S[d][j4+3] = v.w;
        } else {
            #pragma unroll
            for (int c = 0; c < 4; ++c) {
                int u = u0 + j4 + c;
                S[d][j4+c] = (u < U_) ? src[c] : 0.f;
            }
        }
    }
    __syncthreads();
    int h = h0 + (tid & 127);
    int ug = tid >> 7;
    float acc[8] = {0.f,0.f,0.f,0.f,0.f,0.f,0.f,0.f};
    for (int d = 0; d < DDEC; ++d) {
        float w = W[(size_t)d * H_ + h];
        const float* e = &S[d][ug * 8];
        #pragma unroll
        for (int i = 0; i < 8; ++i) acc[i] += w * e[i];
    }
    float bb = bias[h];
    #pragma unroll
    for (int i = 0; i < 8; ++i) {
        int u = u0 + ug * 8 + i;
        if (u < U_) out[((size_t)b * U_ + u) * H_ + h] = acc[i] + bb;
    }
}

// ---------------- K3: Wt[v][h] = bf16(W_out[h][v]), v padded to VPAD with zeros
__global__ __launch_bounds__(256) void wt_transpose_kernel(
    const float* __restrict__ W, unsigned short* __restrict__ Wt)
{
    int hc = blockIdx.x, vc = blockIdx.y;
    int h0 = hc * 64, v0 = vc * 64;
    __shared__ float tile[64][65];
    int tid = threadIdx.x;
    #pragma unroll
    for (int it = 0; it < 16; ++it) {
        int hl = it * 4 + (tid >> 6);
        int vl = tid & 63;
        int v = v0 + vl;
        tile[hl][vl] = (v < V_) ? W[(size_t)(h0 + hl) * V_ + v] : 0.f;
    }
    __syncthreads();
    #pragma unroll
    for (int it = 0; it < 16; ++it) {
        int vl = it * 4 + (tid >> 6);
        int hl = tid & 63;
        __bf16 bv = (__bf16)tile[hl][vl];
        Wt[(size_t)(v0 + vl) * H_ + h0 + hl] = *(unsigned short*)&bv;
    }
}

// ---------------- K4: main fused joint kernel
// block tile: 128 rows (16 t x 8 u) x 128 v-cols; 4 waves (2x2), wave = 64x64
__global__ __launch_bounds__(256, 2) void joint_kernel(
    const float* __restrict__ encP,            // [B,T,H]
    const float* __restrict__ decP,            // [B,U,H]
    const unsigned short* __restrict__ Wt,     // [VPAD][H] bf16
    const float* __restrict__ b_out,           // [V]
    float* __restrict__ out)                   // [B,T,U,V]
{
    constexpr int LDW = H_ + 4;                // 644 dwords: spreads LDS banks
    __shared__ float encS[16][LDW];            // 41.2 KB
    __shared__ float decS[8][LDW];             // 20.6 KB
    int nt = blockIdx.x;                       // 0..8   (v tile)
    int tu = blockIdx.y;                       // 0..168 (t,u tile)
    int b  = blockIdx.z;
    int tt = tu / 13, ut = tu % 13;
    int t0 = tt * 16, u0 = ut * 8, vb = nt * 128;
    int tid = threadIdx.x;

    // stage enc rows (16 x 640 f32) and dec rows (8 x 640 f32) for whole K
    for (int s = tid; s < 16 * (H_ / 4); s += 256) {
        int r = s / 160, k4 = (s % 160) * 4;
        int t = t0 + r; if (t > T_ - 1) t = T_ - 1;
        float4 v = *(const float4*)(encP + ((size_t)b * T_ + t) * H_ + k4);
        *(float4*)&encS[r][k4] = v;
    }
    for (int s = tid; s < 8 * (H_ / 4); s += 256) {
        int r = s / 160, k4 = (s % 160) * 4;
        int u = u0 + r; if (u > U_ - 1) u = U_ - 1;
        float4 v = *(const float4*)(decP + ((size_t)b * U_ + u) * H_ + k4);
        *(float4*)&decS[r][k4] = v;
    }
    __syncthreads();

    int lane = tid & 63, wid = tid >> 6;
    int wr = wid >> 1, wc = wid & 1;
    int lrow = lane & 15, kg = lane >> 4, koff = kg * 8;

    const float* ep[4];
    const float* dp[4];
    #pragma unroll
    for (int i = 0; i < 4; ++i) {
        int row = wr * 64 + i * 16 + lrow;
        ep[i] = &encS[row >> 3][koff];
        dp[i] = &decS[row & 7][koff];
    }
    const unsigned short* wp[4];
    #pragma unroll
    for (int j = 0; j < 4; ++j) {
        int v = vb + wc * 64 + j * 16 + lrow;
        wp[j] = Wt + (size_t)v * H_ + koff;
    }

    f32x4 acc[4][4];
    #pragma unroll
    for (int i = 0; i < 4; ++i)
        #pragma unroll
        for (int j = 0; j < 4; ++j)
            acc[i][j] = (f32x4){0.f, 0.f, 0.f, 0.f};

    for (int kk = 0; kk < H_; kk += 32) {
        bf16x8 a[4];
        #pragma unroll
        for (int i = 0; i < 4; ++i) {
            float4 e0 = *(const float4*)(ep[i] + kk);
            float4 e1 = *(const float4*)(ep[i] + kk + 4);
            float4 f0 = *(const float4*)(dp[i] + kk);
            float4 f1 = *(const float4*)(dp[i] + kk + 4);
            bf16x8 av;
            av[0] = (__bf16)fmaxf(e0.x + f0.x, 0.f);
            av[1] = (__bf16)fmaxf(e0.y + f0.y, 0.f);
            av[2] = (__bf16)fmaxf(e0.z + f0.z, 0.f);
            av[3] = (__bf16)fmaxf(e0.w + f0.w, 0.f);
            av[4] = (__bf16)fmaxf(e1.x + f1.x, 0.f);
            av[5] = (__bf16)fmaxf(e1.y + f1.y, 0.f);
            av[6] = (__bf16)fmaxf(e1.z + f1.z, 0.f);
            av[7] = (__bf16)fmaxf(e1.w + f1.w, 0.f);
            a[i] = av;
        }
        bf16x8 bq[4];
        #pragma unroll
        for (int j = 0; j < 4; ++j)
            bq[j] = *(const bf16x8*)(wp[j] + kk);
        #pragma unroll
        for (int i = 0; i < 4; ++i)
            #pragma unroll
            for (int j = 0; j < 4; ++j)
                acc[i][j] = __builtin_amdgcn_mfma_f32_16x16x32_bf16(a[i], bq[j], acc[i][j], 0, 0, 0);
    }

    // epilogue: D layout col = lane&15, row = (lane>>4)*4 + q
    #pragma unroll
    for (int j = 0; j < 4; ++j) {
        int v = vb + wc * 64 + j * 16 + lrow;
        float bo = (v < V_) ? b_out[v] : 0.f;
        #pragma unroll
        for (int i = 0; i < 4; ++i) {
            #pragma unroll
            for (int q = 0; q < 4; ++q) {
                int row = wr * 64 + i * 16 + kg * 4 + q;
                int t = t0 + (row >> 3);
                int u = u0 + (row & 7);
                if (t < T_ && u < U_ && v < V_)
                    out[(((size_t)b * T_ + t) * U_ + u) * V_ + v] = acc[i][j][q] + bo;
            }
        }
    }
}

extern "C" void kernel_launch(void* const* d_in, const int* in_sizes, int n_in,
                              void* d_out, int out_size, void* d_ws, size_t ws_size,
                              hipStream_t stream) {
    const float* enc    = (const float*)d_in[0];   // [4,512,200]
    const float* dec    = (const float*)d_in[1];   // [4,640,100]
    const float* W_enc  = (const float*)d_in[2];   // [512,640]
    const float* b_enc  = (const float*)d_in[3];   // [640]
    const float* W_pred = (const float*)d_in[4];   // [640,640]
    const float* b_pred = (const float*)d_in[5];   // [640]
    const float* W_out  = (const float*)d_in[6];   // [640,1025]
    const float* b_out  = (const float*)d_in[7];   // [1025]
    float* out = (float*)d_out;

    char* ws = (char*)d_ws;
    float* encP = (float*)ws;                                  // 4*200*640*4 = 2,048,000
    float* decP = (float*)(ws + 2048000);                      // 4*100*640*4 = 1,024,000
    unsigned short* Wt = (unsigned short*)(ws + 2048000 + 1024000); // 1152*640*2 = 1,474,560

    enc_proj_kernel<<<dim3(5, 13, 4), 256, 0, stream>>>(enc, W_enc, b_enc, encP);
    dec_proj_kernel<<<dim3(5, 7, 4), 256, 0, stream>>>(dec, W_pred, b_pred, decP);
    wt_transpose_kernel<<<dim3(10, 18), 256, 0, stream>>>(W_out, Wt);
    joint_kernel<<<dim3(9, 169, 4), 256, 0, stream>>>(encP, decP, Wt, b_out, out);
}